// Round 2
// baseline (8162.280 us; speedup 1.0000x reference)
//
#include <hip/hip_runtime.h>
#include <math.h>

#define T_ 8
#define N_ 100000
#define E_ 1600000
#define F_ 17
#define G_ 32
#define H_ 48
#define SCAN_NB 98        // ceil(N/1024)
#define CONV_GRID 2048
#define FP 20             // F padded to multiple of 4 (zero-padded)
#define RP 52             // conv2 LDS row stride (48 + 4 pad, breaks bank aliasing)

// ---------------- CSR build ----------------
__global__ void k_count(const int* __restrict__ dst, int* __restrict__ cnt) {
    int e = blockIdx.x * blockDim.x + threadIdx.x;
    if (e < E_) atomicAdd(&cnt[dst[e]], 1);
}

__global__ void k_scan1(const int* __restrict__ cnt, int* __restrict__ bsum) {
    __shared__ int s[256];
    int b = blockIdx.x, tid = threadIdx.x;
    int i0 = b * 1024 + tid * 4;
    int v = 0;
#pragma unroll
    for (int j = 0; j < 4; ++j) { int i = i0 + j; if (i < N_) v += cnt[i]; }
    s[tid] = v; __syncthreads();
    for (int off = 128; off > 0; off >>= 1) {
        if (tid < off) s[tid] += s[tid + off];
        __syncthreads();
    }
    if (tid == 0) bsum[b] = s[0];
}

__global__ void k_scan2(int* bsum, int* rowp) {
    if (threadIdx.x == 0) {
        int off = 0;
        for (int b = 0; b < SCAN_NB; ++b) { int v = bsum[b]; bsum[b] = off; off += v; }
        rowp[N_] = E_;
    }
}

// writes rowp[i] (pristine, for deg) and overwrites cnt[i] with same value (cursor)
__global__ void k_scan3(int* __restrict__ cnt, const int* __restrict__ bsum,
                        int* __restrict__ rowp) {
    __shared__ int s[256];
    int b = blockIdx.x, tid = threadIdx.x;
    int i0 = b * 1024 + tid * 4;
    int c[4]; int tsum = 0;
#pragma unroll
    for (int j = 0; j < 4; ++j) { int i = i0 + j; c[j] = (i < N_) ? cnt[i] : 0; tsum += c[j]; }
    s[tid] = tsum; __syncthreads();
    for (int off = 1; off < 256; off <<= 1) {
        int v = 0;
        if (tid >= off) v = s[tid - off];
        __syncthreads();
        s[tid] += v;
        __syncthreads();
    }
    int base = bsum[b] + s[tid] - tsum;
#pragma unroll
    for (int j = 0; j < 4; ++j) {
        int i = i0 + j;
        if (i < N_) { rowp[i] = base; cnt[i] = base; base += c[j]; }
    }
}

__global__ void k_fill(const int* __restrict__ src, const int* __restrict__ dst,
                       int* __restrict__ cursor, int* __restrict__ srcs) {
    int e = blockIdx.x * blockDim.x + threadIdx.x;
    if (e < E_) {
        int pos = atomicAdd(&cursor[dst[e]], 1);
        srcs[pos] = src[e];
    }
}

// ---------------- conv1 (fused gather + dual linear + relu) ----------------
// 192 threads, 16 nodes/group: thread (q,h) owns nodes g*16+q*4+{0..3}, dim h
__global__ __launch_bounds__(192) void k_conv1(
        const float* __restrict__ x, const int* __restrict__ rowp,
        const int* __restrict__ srcs,
        const float* __restrict__ Ws1, const float* __restrict__ bs1,
        const float* __restrict__ Wn1, const float* __restrict__ bn1,
        float* __restrict__ h1) {
    __shared__ __attribute__((aligned(16))) float wsT[FP * H_];
    __shared__ __attribute__((aligned(16))) float wnT[FP * H_];
    __shared__ __attribute__((aligned(16))) float shx[16 * FP];
    __shared__ __attribute__((aligned(16))) float sha[16 * FP];
    __shared__ float bsum[H_];
    int tid = threadIdx.x;
    for (int i = tid; i < FP * H_; i += 192) {
        int k = i / H_, h = i - k * H_;
        wsT[i] = (k < F_) ? Ws1[h * F_ + k] : 0.f;
        wnT[i] = (k < F_) ? Wn1[h * F_ + k] : 0.f;
    }
    if (tid < H_) bsum[tid] = bs1[tid] + bn1[tid];
    int q = tid / H_, h = tid - q * H_;
    const int ngroups = N_ / 16;
    for (int g = blockIdx.x; g < ngroups; g += gridDim.x) {
        __syncthreads();
        for (int i = tid; i < 16 * FP; i += 192) {
            int row = i / FP, k = i - row * FP;
            shx[i] = (k < F_) ? x[(g * 16 + row) * F_ + k] : 0.f;
        }
#pragma unroll
        for (int c = 0; c < 4; ++c) {
            int n = g * 16 + q * 4 + c;
            if (h < F_) {
                int base = rowp[n], dg = rowp[n + 1] - base;
                float acc = 0.f;
                for (int j = 0; j < dg; ++j)
                    acc += x[srcs[base + j] * F_ + h];
                sha[(q * 4 + c) * FP + h] = acc / fmaxf((float)dg, 1.f);
            } else if (h < FP) {
                sha[(q * 4 + c) * FP + h] = 0.f;
            }
        }
        __syncthreads();
        float acc[4];
#pragma unroll
        for (int c = 0; c < 4; ++c) acc[c] = bsum[h];
#pragma unroll
        for (int k4 = 0; k4 < FP / 4; ++k4) {
            float w_s[4], w_n[4];
#pragma unroll
            for (int j = 0; j < 4; ++j) {
                w_s[j] = wsT[(k4 * 4 + j) * H_ + h];
                w_n[j] = wnT[(k4 * 4 + j) * H_ + h];
            }
#pragma unroll
            for (int c = 0; c < 4; ++c) {
                const float4 xv = *(const float4*)&shx[(q * 4 + c) * FP + k4 * 4];
                const float4 av = *(const float4*)&sha[(q * 4 + c) * FP + k4 * 4];
                acc[c] += xv.x * w_s[0] + xv.y * w_s[1] + xv.z * w_s[2] + xv.w * w_s[3]
                        + av.x * w_n[0] + av.y * w_n[1] + av.z * w_n[2] + av.w * w_n[3];
            }
        }
#pragma unroll
        for (int c = 0; c < 4; ++c)
            h1[(g * 16 + q * 4 + c) * H_ + h] = fmaxf(acc[c], 0.f);
    }
}

// ---------------- conv2 + spatial mask + pooled partials ----------------
__global__ __launch_bounds__(192) void k_conv2(
        const float* __restrict__ h1, const int* __restrict__ rowp,
        const int* __restrict__ srcs,
        const float* __restrict__ Ws2, const float* __restrict__ bs2,
        const float* __restrict__ Wn2, const float* __restrict__ bn2,
        const float* __restrict__ Wsm, const float* __restrict__ bsm,
        float* __restrict__ sm_out, float* __restrict__ partial) {
    __shared__ __attribute__((aligned(16))) float wsT[H_ * H_];
    __shared__ __attribute__((aligned(16))) float wnT[H_ * H_];
    __shared__ __attribute__((aligned(16))) float wmT[H_ * H_];
    __shared__ __attribute__((aligned(16))) float shh[16 * RP];
    __shared__ __attribute__((aligned(16))) float sha[16 * RP];
    __shared__ __attribute__((aligned(16))) float shh2[16 * RP];
    __shared__ float bsum[H_], bm[H_], psum[H_];
    int tid = threadIdx.x;
    for (int i = tid; i < H_ * H_; i += 192) {
        int k = i / H_, h = i - k * H_;
        wsT[i] = Ws2[h * H_ + k];
        wnT[i] = Wn2[h * H_ + k];
        wmT[i] = Wsm[h * H_ + k];
    }
    if (tid < H_) { bsum[tid] = bs2[tid] + bn2[tid]; bm[tid] = bsm[tid]; psum[tid] = 0.f; }
    int q = tid / H_, h = tid - q * H_;
    float pacc = 0.f;
    const int ngroups = N_ / 16;
    for (int g = blockIdx.x; g < ngroups; g += gridDim.x) {
        __syncthreads();
        {   // stage the 16 own-rows (768 contiguous floats) as float4
            int row = tid / 12, kk = (tid - row * 12) * 4;
            const float4 v = *(const float4*)&h1[(g * 16 + row) * H_ + kk];
            *(float4*)&shh[row * RP + kk] = v;
        }
#pragma unroll
        for (int c = 0; c < 4; ++c) {
            int n = g * 16 + q * 4 + c;
            int base = rowp[n], dg = rowp[n + 1] - base;
            float s = 0.f;
            for (int j = 0; j < dg; ++j)
                s += h1[srcs[base + j] * H_ + h];
            sha[(q * 4 + c) * RP + h] = s / fmaxf((float)dg, 1.f);
        }
        __syncthreads();
        float acc[4];
#pragma unroll
        for (int c = 0; c < 4; ++c) acc[c] = bsum[h];
#pragma unroll
        for (int k4 = 0; k4 < H_ / 4; ++k4) {
            float w_s[4], w_n[4];
#pragma unroll
            for (int j = 0; j < 4; ++j) {
                w_s[j] = wsT[(k4 * 4 + j) * H_ + h];
                w_n[j] = wnT[(k4 * 4 + j) * H_ + h];
            }
#pragma unroll
            for (int c = 0; c < 4; ++c) {
                const float4 hv = *(const float4*)&shh[(q * 4 + c) * RP + k4 * 4];
                const float4 av = *(const float4*)&sha[(q * 4 + c) * RP + k4 * 4];
                acc[c] += hv.x * w_s[0] + hv.y * w_s[1] + hv.z * w_s[2] + hv.w * w_s[3]
                        + av.x * w_n[0] + av.y * w_n[1] + av.z * w_n[2] + av.w * w_n[3];
            }
        }
        float h2v[4];
#pragma unroll
        for (int c = 0; c < 4; ++c) {
            h2v[c] = fmaxf(acc[c], 0.f);
            shh2[(q * 4 + c) * RP + h] = h2v[c];
        }
        __syncthreads();
        float macc[4];
#pragma unroll
        for (int c = 0; c < 4; ++c) macc[c] = bm[h];
#pragma unroll
        for (int k4 = 0; k4 < H_ / 4; ++k4) {
            float w_m[4];
#pragma unroll
            for (int j = 0; j < 4; ++j) w_m[j] = wmT[(k4 * 4 + j) * H_ + h];
#pragma unroll
            for (int c = 0; c < 4; ++c) {
                const float4 hv = *(const float4*)&shh2[(q * 4 + c) * RP + k4 * 4];
                macc[c] += hv.x * w_m[0] + hv.y * w_m[1] + hv.z * w_m[2] + hv.w * w_m[3];
            }
        }
#pragma unroll
        for (int c = 0; c < 4; ++c) {
            int n = g * 16 + q * 4 + c;
            float smv = 1.f / (1.f + expf(-macc[c]));
            sm_out[(size_t)n * H_ + h] = smv;
            pacc += h2v[c] * smv;
        }
    }
    __syncthreads();
    atomicAdd(&psum[h], pacc);
    __syncthreads();
    if (tid < H_) partial[tid * CONV_GRID + blockIdx.x] = psum[tid];
}

// ---------------- pooled reduction: 384 blocks, one per (t,h) ----------------
__global__ void k_reduce(const float* __restrict__ partial, float* __restrict__ pooled) {
    __shared__ float s[256];
    int b = blockIdx.x, tid = threadIdx.x;
    const float* p = partial + (size_t)b * CONV_GRID;
    float v = 0.f;
    for (int i = tid; i < CONV_GRID; i += 256) v += p[i];
    s[tid] = v; __syncthreads();
    for (int off = 128; off > 0; off >>= 1) {
        if (tid < off) s[tid] += s[tid + off];
        __syncthreads();
    }
    if (tid == 0) pooled[b] = s[0];
}

// ---------------- tail: seq build, GRU, attention, regressor, top8 -----------
__global__ void k_final(const float* __restrict__ gf_all, const float* __restrict__ pooled,
                        const float* __restrict__ Wgp, const float* __restrict__ bgp,
                        const float* __restrict__ W_ih, const float* __restrict__ b_ih,
                        const float* __restrict__ W_hh, const float* __restrict__ b_hh,
                        const float* __restrict__ Wa, const float* __restrict__ ba,
                        const float* __restrict__ Wtm, const float* __restrict__ btm,
                        const float* __restrict__ Wr1, const float* __restrict__ br1,
                        const float* __restrict__ Wr2, const float* __restrict__ br2,
                        const float* __restrict__ Ws1,
                        float* __restrict__ out) {
    __shared__ float seq[T_][2 * H_];
    __shared__ float hstate[H_];
    __shared__ float gout[T_][H_];
    __shared__ float tmp[H_];
    __shared__ float scores[T_], tmask[T_], wts[T_];
    __shared__ float ctx[H_], reg[H_];
    int tid = threadIdx.x;  // 64 threads

    if (tid < H_) {
        for (int t = 0; t < T_; ++t) {
            seq[t][tid] = pooled[t * H_ + tid] / (float)N_;
            float acc = bgp[tid];
            for (int k = 0; k < G_; ++k) acc += Wgp[tid * G_ + k] * gf_all[t * G_ + k];
            seq[t][H_ + tid] = fmaxf(acc, 0.0f);
        }
        hstate[tid] = 0.0f;
    }
    __syncthreads();

    for (int t = 0; t < T_; ++t) {
        if (tid < H_) {
            float gi_r = b_ih[tid], gi_z = b_ih[H_ + tid], gi_n = b_ih[2 * H_ + tid];
            for (int k = 0; k < 2 * H_; ++k) {
                float xv = seq[t][k];
                gi_r += W_ih[tid * 2 * H_ + k] * xv;
                gi_z += W_ih[(H_ + tid) * 2 * H_ + k] * xv;
                gi_n += W_ih[(2 * H_ + tid) * 2 * H_ + k] * xv;
            }
            float gh_r = b_hh[tid], gh_z = b_hh[H_ + tid], gh_n = b_hh[2 * H_ + tid];
            for (int k = 0; k < H_; ++k) {
                float hv = hstate[k];
                gh_r += W_hh[tid * H_ + k] * hv;
                gh_z += W_hh[(H_ + tid) * H_ + k] * hv;
                gh_n += W_hh[(2 * H_ + tid) * H_ + k] * hv;
            }
            float r = 1.0f / (1.0f + expf(-(gi_r + gh_r)));
            float z = 1.0f / (1.0f + expf(-(gi_z + gh_z)));
            float nn = tanhf(gi_n + r * gh_n);
            tmp[tid] = (1.0f - z) * nn + z * hstate[tid];
        }
        __syncthreads();
        if (tid < H_) {
            hstate[tid] = tmp[tid];
            gout[t][tid] = tmp[tid];
        }
        __syncthreads();
    }

    if (tid < T_) {
        float s = ba[0], m = btm[0];
        for (int k = 0; k < H_; ++k) {
            s += Wa[k] * gout[tid][k];
            m += Wtm[k] * gout[tid][k];
        }
        scores[tid] = s;
        tmask[tid] = 1.0f / (1.0f + expf(-m));
    }
    __syncthreads();
    if (tid == 0) {
        float mx = scores[0];
        for (int t = 1; t < T_; ++t) mx = fmaxf(mx, scores[t]);
        float sum = 0.0f;
        for (int t = 0; t < T_; ++t) { wts[t] = expf(scores[t] - mx); sum += wts[t]; }
        for (int t = 0; t < T_; ++t) {
            wts[t] /= sum;
            out[1 + t] = wts[t];
            out[17 + (size_t)T_ * N_ * H_ + t] = tmask[t];
        }
    }
    __syncthreads();
    if (tid < H_) {
        float c = 0.0f;
        for (int t = 0; t < T_; ++t) c += gout[t][tid] * wts[t] * tmask[t];
        ctx[tid] = c;
    }
    __syncthreads();
    if (tid < H_) {
        float acc = br1[tid];
        for (int k = 0; k < H_; ++k) acc += Wr1[tid * H_ + k] * ctx[k];
        reg[tid] = fmaxf(acc, 0.0f);
    }
    __syncthreads();
    if (tid == 0) {
        float p = br2[0];
        for (int k = 0; k < H_; ++k) p += Wr2[k] * reg[k];
        out[0] = p;
        float m[F_];
        for (int f = 0; f < F_; ++f) {
            float s = 0.0f;
            for (int h = 0; h < H_; ++h) s += fabsf(Ws1[h * F_ + f]);
            m[f] = s / (float)H_;
        }
        for (int i = 0; i < 8; ++i) {
            int best = i;
            for (int j = i + 1; j < F_; ++j)
                if (m[j] > m[best]) best = j;
            float tv = m[i]; m[i] = m[best]; m[best] = tv;
            out[9 + i] = m[i];
        }
    }
}

extern "C" void kernel_launch(void* const* d_in, const int* in_sizes, int n_in,
                              void* d_out, int out_size, void* d_ws, size_t ws_size,
                              hipStream_t stream) {
    const float* node_features  = (const float*)d_in[0];
    const int*   edge_index     = (const int*)d_in[1];
    const float* graph_features = (const float*)d_in[2];
    const float* Ws1 = (const float*)d_in[3];
    const float* bs1 = (const float*)d_in[4];
    const float* Wn1 = (const float*)d_in[5];
    const float* bn1 = (const float*)d_in[6];
    const float* Ws2 = (const float*)d_in[7];
    const float* bs2 = (const float*)d_in[8];
    const float* Wn2 = (const float*)d_in[9];
    const float* bn2 = (const float*)d_in[10];
    const float* Wgp = (const float*)d_in[11];
    const float* bgp = (const float*)d_in[12];
    const float* W_ih = (const float*)d_in[13];
    const float* b_ih = (const float*)d_in[14];
    const float* W_hh = (const float*)d_in[15];
    const float* b_hh = (const float*)d_in[16];
    const float* Wa  = (const float*)d_in[17];
    const float* ba  = (const float*)d_in[18];
    const float* Wsm = (const float*)d_in[19];
    const float* bsm = (const float*)d_in[20];
    const float* Wtm = (const float*)d_in[21];
    const float* btm = (const float*)d_in[22];
    const float* Wr1 = (const float*)d_in[23];
    const float* br1 = (const float*)d_in[24];
    const float* Wr2 = (const float*)d_in[25];
    const float* br2 = (const float*)d_in[26];

    // workspace layout (~29.5 MB)
    int* cnt   = (int*)d_ws;                         // N (count -> cursor)
    int* rowp  = cnt + N_;                           // N+1
    int* bsum  = rowp + (N_ + 1);                    // 128
    int* srcs  = bsum + 128;                         // E
    float* h1      = (float*)(srcs + E_);            // N*H
    float* partial = h1 + (size_t)N_ * H_;           // T*H*CONV_GRID
    float* pooled  = partial + (size_t)T_ * H_ * CONV_GRID;  // T*H

    float* out = (float*)d_out;

    for (int t = 0; t < T_; ++t) {
        const float* x   = node_features + (size_t)t * N_ * F_;
        const int*   src = edge_index + (size_t)t * 2 * E_;
        const int*   dst = src + E_;

        hipMemsetAsync(cnt, 0, N_ * sizeof(int), stream);
        k_count<<<(E_ + 255) / 256, 256, 0, stream>>>(dst, cnt);
        k_scan1<<<SCAN_NB, 256, 0, stream>>>(cnt, bsum);
        k_scan2<<<1, 64, 0, stream>>>(bsum, rowp);
        k_scan3<<<SCAN_NB, 256, 0, stream>>>(cnt, bsum, rowp);
        k_fill<<<(E_ + 255) / 256, 256, 0, stream>>>(src, dst, cnt, srcs);

        k_conv1<<<CONV_GRID, 192, 0, stream>>>(x, rowp, srcs, Ws1, bs1, Wn1, bn1, h1);
        float* sm_out = out + 17 + (size_t)t * N_ * H_;
        k_conv2<<<CONV_GRID, 192, 0, stream>>>(h1, rowp, srcs, Ws2, bs2, Wn2, bn2,
                                               Wsm, bsm, sm_out,
                                               partial + (size_t)t * H_ * CONV_GRID);
    }

    k_reduce<<<T_ * H_, 256, 0, stream>>>(partial, pooled);
    k_final<<<1, 64, 0, stream>>>(graph_features, pooled, Wgp, bgp,
                                  W_ih, b_ih, W_hh, b_hh, Wa, ba, Wtm, btm,
                                  Wr1, br1, Wr2, br2, Ws1, out);
}

// Round 3
// 7587.122 us; speedup vs baseline: 1.0758x; 1.0758x over previous
//
#include <hip/hip_runtime.h>
#include <math.h>

#define T_ 8
#define N_ 100000
#define E_ 1600000
#define F_ 17
#define G_ 32
#define H_ 48
#define SCAN_NB 98        // ceil(N/1024)
#define CONV_GRID 2048
#define FP 20             // F padded to multiple of 4 (zero-padded)
#define RP 52             // conv2 LDS row stride (48 + 4 pad)
#define AGG_NT 32         // nodes per aggregation block

// ---------------- CSR build ----------------
__global__ void k_count(const int* __restrict__ dst, int* __restrict__ cnt) {
    int e = blockIdx.x * blockDim.x + threadIdx.x;
    if (e < E_) atomicAdd(&cnt[dst[e]], 1);
}

__global__ void k_scan1(const int* __restrict__ cnt, int* __restrict__ bsum) {
    __shared__ int s[256];
    int b = blockIdx.x, tid = threadIdx.x;
    int i0 = b * 1024 + tid * 4;
    int v = 0;
#pragma unroll
    for (int j = 0; j < 4; ++j) { int i = i0 + j; if (i < N_) v += cnt[i]; }
    s[tid] = v; __syncthreads();
    for (int off = 128; off > 0; off >>= 1) {
        if (tid < off) s[tid] += s[tid + off];
        __syncthreads();
    }
    if (tid == 0) bsum[b] = s[0];
}

__global__ void k_scan2(int* bsum, int* rowp) {
    if (threadIdx.x == 0) {
        int off = 0;
        for (int b = 0; b < SCAN_NB; ++b) { int v = bsum[b]; bsum[b] = off; off += v; }
        rowp[N_] = E_;
    }
}

__global__ void k_scan3(int* __restrict__ cnt, const int* __restrict__ bsum,
                        int* __restrict__ rowp) {
    __shared__ int s[256];
    int b = blockIdx.x, tid = threadIdx.x;
    int i0 = b * 1024 + tid * 4;
    int c[4]; int tsum = 0;
#pragma unroll
    for (int j = 0; j < 4; ++j) { int i = i0 + j; c[j] = (i < N_) ? cnt[i] : 0; tsum += c[j]; }
    s[tid] = tsum; __syncthreads();
    for (int off = 1; off < 256; off <<= 1) {
        int v = 0;
        if (tid >= off) v = s[tid - off];
        __syncthreads();
        s[tid] += v;
        __syncthreads();
    }
    int base = bsum[b] + s[tid] - tsum;
#pragma unroll
    for (int j = 0; j < 4; ++j) {
        int i = i0 + j;
        if (i < N_) { rowp[i] = base; cnt[i] = base; base += c[j]; }
    }
}

__global__ void k_fill(const int* __restrict__ src, const int* __restrict__ dst,
                       int* __restrict__ cursor, int* __restrict__ srcs) {
    int e = blockIdx.x * blockDim.x + threadIdx.x;
    if (e < E_) {
        int pos = atomicAdd(&cursor[dst[e]], 1);
        srcs[pos] = src[e];
    }
}

// ---------------- edge-parallel aggregation, conv1 (17-dim) ----------------
// block owns 32 nodes; flat work = L_edges * 17 scalar adds into LDS
__global__ __launch_bounds__(256) void k_agg1(
        const float* __restrict__ x, const int* __restrict__ rowp,
        const int* __restrict__ srcs, float* __restrict__ neigh /* [N][FP] */) {
    __shared__ float agg[AGG_NT][FP];
    __shared__ int srp[AGG_NT + 1];
    int tid = threadIdx.x;
    int n0 = blockIdx.x * AGG_NT;
    if (tid <= AGG_NT) srp[tid] = rowp[n0 + tid];
    for (int i = tid; i < AGG_NT * FP; i += 256) ((float*)agg)[i] = 0.f;
    __syncthreads();
    int base = srp[0];
    int L = srp[AGG_NT] - base;
    for (unsigned w = tid; w < (unsigned)(L * F_); w += 256) {
        unsigned e = w / F_;
        int k = (int)(w - e * F_);
        int ge = base + (int)e;
        int s = srcs[ge];
        int lo = 0, hi = AGG_NT;
        while (hi - lo > 1) { int mid = (lo + hi) >> 1; if (ge >= srp[mid]) lo = mid; else hi = mid; }
        atomicAdd(&agg[lo][k], x[s * F_ + k]);
    }
    __syncthreads();
    for (int i = tid; i < AGG_NT * FP; i += 256) {
        int nl = i / FP, k = i - nl * FP;
        int dg = srp[nl + 1] - srp[nl];
        float inv = 1.f / fmaxf((float)dg, 1.f);
        neigh[(size_t)(n0 + nl) * FP + k] = agg[nl][k] * inv;  // pad cols stay 0
    }
}

// ---------------- edge-parallel aggregation, conv2 (48-dim, float4) --------
__global__ __launch_bounds__(256) void k_agg2(
        const float* __restrict__ h1, const int* __restrict__ rowp,
        const int* __restrict__ srcs, float* __restrict__ neigh /* [N][H] */) {
    __shared__ float agg[AGG_NT][RP];
    __shared__ int srp[AGG_NT + 1];
    int tid = threadIdx.x;
    int n0 = blockIdx.x * AGG_NT;
    if (tid <= AGG_NT) srp[tid] = rowp[n0 + tid];
    for (int i = tid; i < AGG_NT * RP; i += 256) ((float*)agg)[i] = 0.f;
    __syncthreads();
    int base = srp[0];
    int L = srp[AGG_NT] - base;
    for (unsigned w = tid; w < (unsigned)(L * 12); w += 256) {
        unsigned e = w / 12u;
        int f4 = (int)(w - e * 12u);
        int ge = base + (int)e;
        int s = srcs[ge];
        int lo = 0, hi = AGG_NT;
        while (hi - lo > 1) { int mid = (lo + hi) >> 1; if (ge >= srp[mid]) lo = mid; else hi = mid; }
        const float4 v = *(const float4*)&h1[(size_t)s * H_ + f4 * 4];
        float* a = &agg[lo][f4 * 4];
        atomicAdd(a + 0, v.x); atomicAdd(a + 1, v.y);
        atomicAdd(a + 2, v.z); atomicAdd(a + 3, v.w);
    }
    __syncthreads();
    for (int i = tid; i < AGG_NT * H_; i += 256) {
        int nl = i / H_, k = i - nl * H_;
        int dg = srp[nl + 1] - srp[nl];
        float inv = 1.f / fmaxf((float)dg, 1.f);
        neigh[(size_t)(n0 + nl) * H_ + k] = agg[nl][k] * inv;
    }
}

// ---------------- conv1 transform: h1 = relu(x@Ws1.T + neigh@Wn1.T + b) ----
__global__ __launch_bounds__(192) void k_conv1T(
        const float* __restrict__ x, const float* __restrict__ neigh,
        const float* __restrict__ Ws1, const float* __restrict__ bs1,
        const float* __restrict__ Wn1, const float* __restrict__ bn1,
        float* __restrict__ h1) {
    __shared__ __attribute__((aligned(16))) float wsT[FP * H_];
    __shared__ __attribute__((aligned(16))) float wnT[FP * H_];
    __shared__ __attribute__((aligned(16))) float shx[16 * FP];
    __shared__ __attribute__((aligned(16))) float sna[16 * FP];
    __shared__ float bsum_s[H_];
    int tid = threadIdx.x;
    for (int i = tid; i < FP * H_; i += 192) {
        int k = i / H_, h = i - k * H_;
        wsT[i] = (k < F_) ? Ws1[h * F_ + k] : 0.f;
        wnT[i] = (k < F_) ? Wn1[h * F_ + k] : 0.f;
    }
    if (tid < H_) bsum_s[tid] = bs1[tid] + bn1[tid];
    int q = tid / H_, h = tid - q * H_;
    const int ngroups = N_ / 16;
    for (int g = blockIdx.x; g < ngroups; g += gridDim.x) {
        __syncthreads();
        for (int i = tid; i < 16 * FP; i += 192) {
            int row = i / FP, k = i - row * FP;
            shx[i] = (k < F_) ? x[(g * 16 + row) * F_ + k] : 0.f;
        }
        for (int i = tid; i < 16 * 5; i += 192) {
            int row = i / 5, k4 = i - row * 5;
            *(float4*)&sna[row * FP + k4 * 4] =
                *(const float4*)&neigh[(size_t)(g * 16 + row) * FP + k4 * 4];
        }
        __syncthreads();
        float acc[4];
#pragma unroll
        for (int c = 0; c < 4; ++c) acc[c] = bsum_s[h];
#pragma unroll
        for (int k4 = 0; k4 < FP / 4; ++k4) {
            float w_s[4], w_n[4];
#pragma unroll
            for (int j = 0; j < 4; ++j) {
                w_s[j] = wsT[(k4 * 4 + j) * H_ + h];
                w_n[j] = wnT[(k4 * 4 + j) * H_ + h];
            }
#pragma unroll
            for (int c = 0; c < 4; ++c) {
                const float4 xv = *(const float4*)&shx[(q * 4 + c) * FP + k4 * 4];
                const float4 av = *(const float4*)&sna[(q * 4 + c) * FP + k4 * 4];
                acc[c] += xv.x * w_s[0] + xv.y * w_s[1] + xv.z * w_s[2] + xv.w * w_s[3]
                        + av.x * w_n[0] + av.y * w_n[1] + av.z * w_n[2] + av.w * w_n[3];
            }
        }
#pragma unroll
        for (int c = 0; c < 4; ++c)
            h1[(size_t)(g * 16 + q * 4 + c) * H_ + h] = fmaxf(acc[c], 0.f);
    }
}

// ---------------- conv2 transform + spatial mask + pooled partials ---------
__global__ __launch_bounds__(192) void k_conv2T(
        const float* __restrict__ h1, const float* __restrict__ neigh,
        const float* __restrict__ Ws2, const float* __restrict__ bs2,
        const float* __restrict__ Wn2, const float* __restrict__ bn2,
        const float* __restrict__ Wsm, const float* __restrict__ bsm,
        float* __restrict__ sm_out, float* __restrict__ partial) {
    __shared__ __attribute__((aligned(16))) float wsT[H_ * H_];
    __shared__ __attribute__((aligned(16))) float wnT[H_ * H_];
    __shared__ __attribute__((aligned(16))) float wmT[H_ * H_];
    __shared__ __attribute__((aligned(16))) float shh[16 * RP];
    __shared__ __attribute__((aligned(16))) float sna[16 * RP];
    __shared__ __attribute__((aligned(16))) float shh2[16 * RP];
    __shared__ float bsum_s[H_], bm_s[H_], psum[H_];
    int tid = threadIdx.x;
    for (int i = tid; i < H_ * H_; i += 192) {
        int k = i / H_, h = i - k * H_;
        wsT[i] = Ws2[h * H_ + k];
        wnT[i] = Wn2[h * H_ + k];
        wmT[i] = Wsm[h * H_ + k];
    }
    if (tid < H_) { bsum_s[tid] = bs2[tid] + bn2[tid]; bm_s[tid] = bsm[tid]; psum[tid] = 0.f; }
    int q = tid / H_, h = tid - q * H_;
    int srow = tid / 12, sf4 = tid - srow * 12;   // 192 = 16 rows x 12 f4
    float pacc = 0.f;
    const int ngroups = N_ / 16;
    for (int g = blockIdx.x; g < ngroups; g += gridDim.x) {
        __syncthreads();
        *(float4*)&shh[srow * RP + sf4 * 4] =
            *(const float4*)&h1[(size_t)(g * 16 + srow) * H_ + sf4 * 4];
        *(float4*)&sna[srow * RP + sf4 * 4] =
            *(const float4*)&neigh[(size_t)(g * 16 + srow) * H_ + sf4 * 4];
        __syncthreads();
        float acc[4];
#pragma unroll
        for (int c = 0; c < 4; ++c) acc[c] = bsum_s[h];
#pragma unroll
        for (int k4 = 0; k4 < H_ / 4; ++k4) {
            float w_s[4], w_n[4];
#pragma unroll
            for (int j = 0; j < 4; ++j) {
                w_s[j] = wsT[(k4 * 4 + j) * H_ + h];
                w_n[j] = wnT[(k4 * 4 + j) * H_ + h];
            }
#pragma unroll
            for (int c = 0; c < 4; ++c) {
                const float4 hv = *(const float4*)&shh[(q * 4 + c) * RP + k4 * 4];
                const float4 av = *(const float4*)&sna[(q * 4 + c) * RP + k4 * 4];
                acc[c] += hv.x * w_s[0] + hv.y * w_s[1] + hv.z * w_s[2] + hv.w * w_s[3]
                        + av.x * w_n[0] + av.y * w_n[1] + av.z * w_n[2] + av.w * w_n[3];
            }
        }
        float h2v[4];
#pragma unroll
        for (int c = 0; c < 4; ++c) {
            h2v[c] = fmaxf(acc[c], 0.f);
            shh2[(q * 4 + c) * RP + h] = h2v[c];
        }
        __syncthreads();
        float macc[4];
#pragma unroll
        for (int c = 0; c < 4; ++c) macc[c] = bm_s[h];
#pragma unroll
        for (int k4 = 0; k4 < H_ / 4; ++k4) {
            float w_m[4];
#pragma unroll
            for (int j = 0; j < 4; ++j) w_m[j] = wmT[(k4 * 4 + j) * H_ + h];
#pragma unroll
            for (int c = 0; c < 4; ++c) {
                const float4 hv = *(const float4*)&shh2[(q * 4 + c) * RP + k4 * 4];
                macc[c] += hv.x * w_m[0] + hv.y * w_m[1] + hv.z * w_m[2] + hv.w * w_m[3];
            }
        }
#pragma unroll
        for (int c = 0; c < 4; ++c) {
            int n = g * 16 + q * 4 + c;
            float smv = 1.f / (1.f + expf(-macc[c]));
            sm_out[(size_t)n * H_ + h] = smv;
            pacc += h2v[c] * smv;
        }
    }
    __syncthreads();
    atomicAdd(&psum[h], pacc);
    __syncthreads();
    if (tid < H_) partial[tid * CONV_GRID + blockIdx.x] = psum[tid];
}

// ---------------- pooled reduction ----------------
__global__ void k_reduce(const float* __restrict__ partial, float* __restrict__ pooled) {
    __shared__ float s[256];
    int b = blockIdx.x, tid = threadIdx.x;
    const float* p = partial + (size_t)b * CONV_GRID;
    float v = 0.f;
    for (int i = tid; i < CONV_GRID; i += 256) v += p[i];
    s[tid] = v; __syncthreads();
    for (int off = 128; off > 0; off >>= 1) {
        if (tid < off) s[tid] += s[tid + off];
        __syncthreads();
    }
    if (tid == 0) pooled[b] = s[0];
}

// ---------------- tail: seq build, GRU, attention, regressor, top8 ---------
__global__ void k_final(const float* __restrict__ gf_all, const float* __restrict__ pooled,
                        const float* __restrict__ Wgp, const float* __restrict__ bgp,
                        const float* __restrict__ W_ih, const float* __restrict__ b_ih,
                        const float* __restrict__ W_hh, const float* __restrict__ b_hh,
                        const float* __restrict__ Wa, const float* __restrict__ ba,
                        const float* __restrict__ Wtm, const float* __restrict__ btm,
                        const float* __restrict__ Wr1, const float* __restrict__ br1,
                        const float* __restrict__ Wr2, const float* __restrict__ br2,
                        const float* __restrict__ Ws1,
                        float* __restrict__ out) {
    __shared__ float seq[T_][2 * H_];
    __shared__ float hstate[H_];
    __shared__ float gout[T_][H_];
    __shared__ float tmp[H_];
    __shared__ float scores[T_], tmask[T_], wts[T_];
    __shared__ float ctx[H_], reg[H_];
    int tid = threadIdx.x;  // 64 threads

    if (tid < H_) {
        for (int t = 0; t < T_; ++t) {
            seq[t][tid] = pooled[t * H_ + tid] / (float)N_;
            float acc = bgp[tid];
            for (int k = 0; k < G_; ++k) acc += Wgp[tid * G_ + k] * gf_all[t * G_ + k];
            seq[t][H_ + tid] = fmaxf(acc, 0.0f);
        }
        hstate[tid] = 0.0f;
    }
    __syncthreads();

    for (int t = 0; t < T_; ++t) {
        if (tid < H_) {
            float gi_r = b_ih[tid], gi_z = b_ih[H_ + tid], gi_n = b_ih[2 * H_ + tid];
            for (int k = 0; k < 2 * H_; ++k) {
                float xv = seq[t][k];
                gi_r += W_ih[tid * 2 * H_ + k] * xv;
                gi_z += W_ih[(H_ + tid) * 2 * H_ + k] * xv;
                gi_n += W_ih[(2 * H_ + tid) * 2 * H_ + k] * xv;
            }
            float gh_r = b_hh[tid], gh_z = b_hh[H_ + tid], gh_n = b_hh[2 * H_ + tid];
            for (int k = 0; k < H_; ++k) {
                float hv = hstate[k];
                gh_r += W_hh[tid * H_ + k] * hv;
                gh_z += W_hh[(H_ + tid) * H_ + k] * hv;
                gh_n += W_hh[(2 * H_ + tid) * H_ + k] * hv;
            }
            float r = 1.0f / (1.0f + expf(-(gi_r + gh_r)));
            float z = 1.0f / (1.0f + expf(-(gi_z + gh_z)));
            float nn = tanhf(gi_n + r * gh_n);
            tmp[tid] = (1.0f - z) * nn + z * hstate[tid];
        }
        __syncthreads();
        if (tid < H_) {
            hstate[tid] = tmp[tid];
            gout[t][tid] = tmp[tid];
        }
        __syncthreads();
    }

    if (tid < T_) {
        float s = ba[0], m = btm[0];
        for (int k = 0; k < H_; ++k) {
            s += Wa[k] * gout[tid][k];
            m += Wtm[k] * gout[tid][k];
        }
        scores[tid] = s;
        tmask[tid] = 1.0f / (1.0f + expf(-m));
    }
    __syncthreads();
    if (tid == 0) {
        float mx = scores[0];
        for (int t = 1; t < T_; ++t) mx = fmaxf(mx, scores[t]);
        float sum = 0.0f;
        for (int t = 0; t < T_; ++t) { wts[t] = expf(scores[t] - mx); sum += wts[t]; }
        for (int t = 0; t < T_; ++t) {
            wts[t] /= sum;
            out[1 + t] = wts[t];
            out[17 + (size_t)T_ * N_ * H_ + t] = tmask[t];
        }
    }
    __syncthreads();
    if (tid < H_) {
        float c = 0.0f;
        for (int t = 0; t < T_; ++t) c += gout[t][tid] * wts[t] * tmask[t];
        ctx[tid] = c;
    }
    __syncthreads();
    if (tid < H_) {
        float acc = br1[tid];
        for (int k = 0; k < H_; ++k) acc += Wr1[tid * H_ + k] * ctx[k];
        reg[tid] = fmaxf(acc, 0.0f);
    }
    __syncthreads();
    if (tid == 0) {
        float p = br2[0];
        for (int k = 0; k < H_; ++k) p += Wr2[k] * reg[k];
        out[0] = p;
        float m[F_];
        for (int f = 0; f < F_; ++f) {
            float s = 0.0f;
            for (int h = 0; h < H_; ++h) s += fabsf(Ws1[h * F_ + f]);
            m[f] = s / (float)H_;
        }
        for (int i = 0; i < 8; ++i) {
            int best = i;
            for (int j = i + 1; j < F_; ++j)
                if (m[j] > m[best]) best = j;
            float tv = m[i]; m[i] = m[best]; m[best] = tv;
            out[9 + i] = m[i];
        }
    }
}

extern "C" void kernel_launch(void* const* d_in, const int* in_sizes, int n_in,
                              void* d_out, int out_size, void* d_ws, size_t ws_size,
                              hipStream_t stream) {
    const float* node_features  = (const float*)d_in[0];
    const int*   edge_index     = (const int*)d_in[1];
    const float* graph_features = (const float*)d_in[2];
    const float* Ws1 = (const float*)d_in[3];
    const float* bs1 = (const float*)d_in[4];
    const float* Wn1 = (const float*)d_in[5];
    const float* bn1 = (const float*)d_in[6];
    const float* Ws2 = (const float*)d_in[7];
    const float* bs2 = (const float*)d_in[8];
    const float* Wn2 = (const float*)d_in[9];
    const float* bn2 = (const float*)d_in[10];
    const float* Wgp = (const float*)d_in[11];
    const float* bgp = (const float*)d_in[12];
    const float* W_ih = (const float*)d_in[13];
    const float* b_ih = (const float*)d_in[14];
    const float* W_hh = (const float*)d_in[15];
    const float* b_hh = (const float*)d_in[16];
    const float* Wa  = (const float*)d_in[17];
    const float* ba  = (const float*)d_in[18];
    const float* Wsm = (const float*)d_in[19];
    const float* bsm = (const float*)d_in[20];
    const float* Wtm = (const float*)d_in[21];
    const float* btm = (const float*)d_in[22];
    const float* Wr1 = (const float*)d_in[23];
    const float* br1 = (const float*)d_in[24];
    const float* Wr2 = (const float*)d_in[25];
    const float* br2 = (const float*)d_in[26];

    // workspace layout (~49 MB)
    int* cnt   = (int*)d_ws;                         // N (count -> cursor)
    int* rowp  = cnt + N_;                           // N+1
    int* bsum  = rowp + (N_ + 1);                    // 128
    int* srcs  = bsum + 128;                         // E
    float* h1      = (float*)(srcs + E_);            // N*H
    float* neigh   = h1 + (size_t)N_ * H_;           // N*H (conv1 uses [N][FP] prefix)
    float* partial = neigh + (size_t)N_ * H_;        // T*H*CONV_GRID
    float* pooled  = partial + (size_t)T_ * H_ * CONV_GRID;  // T*H

    float* out = (float*)d_out;

    for (int t = 0; t < T_; ++t) {
        const float* x   = node_features + (size_t)t * N_ * F_;
        const int*   src = edge_index + (size_t)t * 2 * E_;
        const int*   dst = src + E_;

        hipMemsetAsync(cnt, 0, N_ * sizeof(int), stream);
        k_count<<<(E_ + 255) / 256, 256, 0, stream>>>(dst, cnt);
        k_scan1<<<SCAN_NB, 256, 0, stream>>>(cnt, bsum);
        k_scan2<<<1, 64, 0, stream>>>(bsum, rowp);
        k_scan3<<<SCAN_NB, 256, 0, stream>>>(cnt, bsum, rowp);
        k_fill<<<(E_ + 255) / 256, 256, 0, stream>>>(src, dst, cnt, srcs);

        k_agg1<<<N_ / AGG_NT, 256, 0, stream>>>(x, rowp, srcs, neigh);
        k_conv1T<<<CONV_GRID, 192, 0, stream>>>(x, neigh, Ws1, bs1, Wn1, bn1, h1);
        k_agg2<<<N_ / AGG_NT, 256, 0, stream>>>(h1, rowp, srcs, neigh);
        float* sm_out = out + 17 + (size_t)t * N_ * H_;
        k_conv2T<<<CONV_GRID, 192, 0, stream>>>(h1, neigh, Ws2, bs2, Wn2, bn2,
                                                Wsm, bsm, sm_out,
                                                partial + (size_t)t * H_ * CONV_GRID);
    }

    k_reduce<<<T_ * H_, 256, 0, stream>>>(partial, pooled);
    k_final<<<1, 64, 0, stream>>>(graph_features, pooled, Wgp, bgp,
                                  W_ih, b_ih, W_hh, b_hh, Wa, ba, Wtm, btm,
                                  Wr1, br1, Wr2, br2, Ws1, out);
}

// Round 4
// 4253.771 us; speedup vs baseline: 1.9188x; 1.7836x over previous
//
#include <hip/hip_runtime.h>
#include <math.h>

#define T_ 8
#define N_ 100000
#define E_ 1600000
#define F_ 17
#define G_ 32
#define H_ 48
#define SCAN_NB 98        // ceil(N/1024)
#define CONV_GRID 2048
#define FP 20             // F padded to multiple of 4 (zero-padded)
#define RP 52             // conv2 LDS row stride (48 + 4 pad)
#define NPW 8             // nodes per wave in aggregation

// ---------------- CSR build ----------------
__global__ void k_count(const int* __restrict__ dst, int* __restrict__ cnt) {
    int e = blockIdx.x * blockDim.x + threadIdx.x;
    if (e < E_) atomicAdd(&cnt[dst[e]], 1);
}

__global__ void k_scan1(const int* __restrict__ cnt, int* __restrict__ bsum) {
    __shared__ int s[256];
    int b = blockIdx.x, tid = threadIdx.x;
    int i0 = b * 1024 + tid * 4;
    int v = 0;
#pragma unroll
    for (int j = 0; j < 4; ++j) { int i = i0 + j; if (i < N_) v += cnt[i]; }
    s[tid] = v; __syncthreads();
    for (int off = 128; off > 0; off >>= 1) {
        if (tid < off) s[tid] += s[tid + off];
        __syncthreads();
    }
    if (tid == 0) bsum[b] = s[0];
}

__global__ void k_scan2(int* bsum, int* rowp) {
    if (threadIdx.x == 0) {
        int off = 0;
        for (int b = 0; b < SCAN_NB; ++b) { int v = bsum[b]; bsum[b] = off; off += v; }
        rowp[N_] = E_;
    }
}

__global__ void k_scan3(int* __restrict__ cnt, const int* __restrict__ bsum,
                        int* __restrict__ rowp) {
    __shared__ int s[256];
    int b = blockIdx.x, tid = threadIdx.x;
    int i0 = b * 1024 + tid * 4;
    int c[4]; int tsum = 0;
#pragma unroll
    for (int j = 0; j < 4; ++j) { int i = i0 + j; c[j] = (i < N_) ? cnt[i] : 0; tsum += c[j]; }
    s[tid] = tsum; __syncthreads();
    for (int off = 1; off < 256; off <<= 1) {
        int v = 0;
        if (tid >= off) v = s[tid - off];
        __syncthreads();
        s[tid] += v;
        __syncthreads();
    }
    int base = bsum[b] + s[tid] - tsum;
#pragma unroll
    for (int j = 0; j < 4; ++j) {
        int i = i0 + j;
        if (i < N_) { rowp[i] = base; cnt[i] = base; base += c[j]; }
    }
}

__global__ void k_fill(const int* __restrict__ src, const int* __restrict__ dst,
                       int* __restrict__ cursor, int* __restrict__ srcs) {
    int e = blockIdx.x * blockDim.x + threadIdx.x;
    if (e < E_) {
        int pos = atomicAdd(&cursor[dst[e]], 1);
        srcs[pos] = src[e];
    }
}

// ---------------- wave-segment mean aggregation (no atomics, no LDS) -------
// wave owns NPW consecutive nodes = contiguous CSR edge range; lane = channel
template<int CH, int STRI, int STRO>
__global__ __launch_bounds__(256) void k_aggW(
        const float* __restrict__ tbl, const int* __restrict__ rowp,
        const int* __restrict__ srcs, float* __restrict__ neigh) {
    int wv = (blockIdx.x * 256 + threadIdx.x) >> 6;
    int lane = threadIdx.x & 63;
    int n0 = wv * NPW;
    if (n0 >= N_) return;
    int n1 = n0 + NPW; if (n1 > N_) n1 = N_;
    int e = rowp[n0];
    const bool act = lane < CH;
    // depth-2 prefetch of gathered rows; depth-3 on src indices
    int s0 = srcs[min(e, E_ - 1)];
    int s1 = srcs[min(e + 1, E_ - 1)];
    float v0 = act ? tbl[(size_t)s0 * STRI + lane] : 0.f;
    float v1 = act ? tbl[(size_t)s1 * STRI + lane] : 0.f;
    int sn = srcs[min(e + 2, E_ - 1)];
    for (int n = n0; n < n1; ++n) {
        int stop = rowp[n + 1];
        int dg = stop - e;
        float acc = 0.f;
        for (; e < stop; ++e) {
            float vn = act ? tbl[(size_t)sn * STRI + lane] : 0.f;
            int sn2 = srcs[min(e + 3, E_ - 1)];
            acc += v0;
            v0 = v1; v1 = vn; sn = sn2;
        }
        if (lane < STRO)
            neigh[(size_t)n * STRO + lane] = acc / fmaxf((float)dg, 1.f);
    }
}

// ---------------- conv1 transform: h1 = relu(x@Ws1.T + neigh@Wn1.T + b) ----
__global__ __launch_bounds__(192) void k_conv1T(
        const float* __restrict__ x, const float* __restrict__ neigh,
        const float* __restrict__ Ws1, const float* __restrict__ bs1,
        const float* __restrict__ Wn1, const float* __restrict__ bn1,
        float* __restrict__ h1) {
    __shared__ __attribute__((aligned(16))) float wsT[FP * H_];
    __shared__ __attribute__((aligned(16))) float wnT[FP * H_];
    __shared__ __attribute__((aligned(16))) float shx[16 * FP];
    __shared__ __attribute__((aligned(16))) float sna[16 * FP];
    __shared__ float bsum_s[H_];
    int tid = threadIdx.x;
    for (int i = tid; i < FP * H_; i += 192) {
        int k = i / H_, h = i - k * H_;
        wsT[i] = (k < F_) ? Ws1[h * F_ + k] : 0.f;
        wnT[i] = (k < F_) ? Wn1[h * F_ + k] : 0.f;
    }
    if (tid < H_) bsum_s[tid] = bs1[tid] + bn1[tid];
    int q = tid / H_, h = tid - q * H_;
    const int ngroups = N_ / 16;
    for (int g = blockIdx.x; g < ngroups; g += gridDim.x) {
        __syncthreads();
        for (int i = tid; i < 16 * FP; i += 192) {
            int row = i / FP, k = i - row * FP;
            shx[i] = (k < F_) ? x[(g * 16 + row) * F_ + k] : 0.f;
        }
        for (int i = tid; i < 16 * 5; i += 192) {
            int row = i / 5, k4 = i - row * 5;
            *(float4*)&sna[row * FP + k4 * 4] =
                *(const float4*)&neigh[(size_t)(g * 16 + row) * FP + k4 * 4];
        }
        __syncthreads();
        float acc[4];
#pragma unroll
        for (int c = 0; c < 4; ++c) acc[c] = bsum_s[h];
#pragma unroll
        for (int k4 = 0; k4 < FP / 4; ++k4) {
            float w_s[4], w_n[4];
#pragma unroll
            for (int j = 0; j < 4; ++j) {
                w_s[j] = wsT[(k4 * 4 + j) * H_ + h];
                w_n[j] = wnT[(k4 * 4 + j) * H_ + h];
            }
#pragma unroll
            for (int c = 0; c < 4; ++c) {
                const float4 xv = *(const float4*)&shx[(q * 4 + c) * FP + k4 * 4];
                const float4 av = *(const float4*)&sna[(q * 4 + c) * FP + k4 * 4];
                acc[c] += xv.x * w_s[0] + xv.y * w_s[1] + xv.z * w_s[2] + xv.w * w_s[3]
                        + av.x * w_n[0] + av.y * w_n[1] + av.z * w_n[2] + av.w * w_n[3];
            }
        }
#pragma unroll
        for (int c = 0; c < 4; ++c)
            h1[(size_t)(g * 16 + q * 4 + c) * H_ + h] = fmaxf(acc[c], 0.f);
    }
}

// ---------------- conv2 transform + spatial mask + pooled partials ---------
__global__ __launch_bounds__(192) void k_conv2T(
        const float* __restrict__ h1, const float* __restrict__ neigh,
        const float* __restrict__ Ws2, const float* __restrict__ bs2,
        const float* __restrict__ Wn2, const float* __restrict__ bn2,
        const float* __restrict__ Wsm, const float* __restrict__ bsm,
        float* __restrict__ sm_out, float* __restrict__ partial) {
    __shared__ __attribute__((aligned(16))) float wsT[H_ * H_];
    __shared__ __attribute__((aligned(16))) float wnT[H_ * H_];
    __shared__ __attribute__((aligned(16))) float wmT[H_ * H_];
    __shared__ __attribute__((aligned(16))) float shh[16 * RP];
    __shared__ __attribute__((aligned(16))) float sna[16 * RP];
    __shared__ __attribute__((aligned(16))) float shh2[16 * RP];
    __shared__ float bsum_s[H_], bm_s[H_], psum[H_];
    int tid = threadIdx.x;
    for (int i = tid; i < H_ * H_; i += 192) {
        int k = i / H_, h = i - k * H_;
        wsT[i] = Ws2[h * H_ + k];
        wnT[i] = Wn2[h * H_ + k];
        wmT[i] = Wsm[h * H_ + k];
    }
    if (tid < H_) { bsum_s[tid] = bs2[tid] + bn2[tid]; bm_s[tid] = bsm[tid]; psum[tid] = 0.f; }
    int q = tid / H_, h = tid - q * H_;
    int srow = tid / 12, sf4 = tid - srow * 12;   // 192 = 16 rows x 12 f4
    float pacc = 0.f;
    const int ngroups = N_ / 16;
    for (int g = blockIdx.x; g < ngroups; g += gridDim.x) {
        __syncthreads();
        *(float4*)&shh[srow * RP + sf4 * 4] =
            *(const float4*)&h1[(size_t)(g * 16 + srow) * H_ + sf4 * 4];
        *(float4*)&sna[srow * RP + sf4 * 4] =
            *(const float4*)&neigh[(size_t)(g * 16 + srow) * H_ + sf4 * 4];
        __syncthreads();
        float acc[4];
#pragma unroll
        for (int c = 0; c < 4; ++c) acc[c] = bsum_s[h];
#pragma unroll
        for (int k4 = 0; k4 < H_ / 4; ++k4) {
            float w_s[4], w_n[4];
#pragma unroll
            for (int j = 0; j < 4; ++j) {
                w_s[j] = wsT[(k4 * 4 + j) * H_ + h];
                w_n[j] = wnT[(k4 * 4 + j) * H_ + h];
            }
#pragma unroll
            for (int c = 0; c < 4; ++c) {
                const float4 hv = *(const float4*)&shh[(q * 4 + c) * RP + k4 * 4];
                const float4 av = *(const float4*)&sna[(q * 4 + c) * RP + k4 * 4];
                acc[c] += hv.x * w_s[0] + hv.y * w_s[1] + hv.z * w_s[2] + hv.w * w_s[3]
                        + av.x * w_n[0] + av.y * w_n[1] + av.z * w_n[2] + av.w * w_n[3];
            }
        }
        float h2v[4];
#pragma unroll
        for (int c = 0; c < 4; ++c) {
            h2v[c] = fmaxf(acc[c], 0.f);
            shh2[(q * 4 + c) * RP + h] = h2v[c];
        }
        __syncthreads();
        float macc[4];
#pragma unroll
        for (int c = 0; c < 4; ++c) macc[c] = bm_s[h];
#pragma unroll
        for (int k4 = 0; k4 < H_ / 4; ++k4) {
            float w_m[4];
#pragma unroll
            for (int j = 0; j < 4; ++j) w_m[j] = wmT[(k4 * 4 + j) * H_ + h];
#pragma unroll
            for (int c = 0; c < 4; ++c) {
                const float4 hv = *(const float4*)&shh2[(q * 4 + c) * RP + k4 * 4];
                macc[c] += hv.x * w_m[0] + hv.y * w_m[1] + hv.z * w_m[2] + hv.w * w_m[3];
            }
        }
#pragma unroll
        for (int c = 0; c < 4; ++c) {
            int n = g * 16 + q * 4 + c;
            float smv = 1.f / (1.f + expf(-macc[c]));
            sm_out[(size_t)n * H_ + h] = smv;
            pacc += h2v[c] * smv;
        }
    }
    __syncthreads();
    atomicAdd(&psum[h], pacc);
    __syncthreads();
    if (tid < H_) partial[tid * CONV_GRID + blockIdx.x] = psum[tid];
}

// ---------------- pooled reduction ----------------
__global__ void k_reduce(const float* __restrict__ partial, float* __restrict__ pooled) {
    __shared__ float s[256];
    int b = blockIdx.x, tid = threadIdx.x;
    const float* p = partial + (size_t)b * CONV_GRID;
    float v = 0.f;
    for (int i = tid; i < CONV_GRID; i += 256) v += p[i];
    s[tid] = v; __syncthreads();
    for (int off = 128; off > 0; off >>= 1) {
        if (tid < off) s[tid] += s[tid + off];
        __syncthreads();
    }
    if (tid == 0) pooled[b] = s[0];
}

// ---------------- tail: seq build, GRU, attention, regressor, top8 ---------
__global__ void k_final(const float* __restrict__ gf_all, const float* __restrict__ pooled,
                        const float* __restrict__ Wgp, const float* __restrict__ bgp,
                        const float* __restrict__ W_ih, const float* __restrict__ b_ih,
                        const float* __restrict__ W_hh, const float* __restrict__ b_hh,
                        const float* __restrict__ Wa, const float* __restrict__ ba,
                        const float* __restrict__ Wtm, const float* __restrict__ btm,
                        const float* __restrict__ Wr1, const float* __restrict__ br1,
                        const float* __restrict__ Wr2, const float* __restrict__ br2,
                        const float* __restrict__ Ws1,
                        float* __restrict__ out) {
    __shared__ float seq[T_][2 * H_];
    __shared__ float hstate[H_];
    __shared__ float gout[T_][H_];
    __shared__ float tmp[H_];
    __shared__ float scores[T_], tmask[T_], wts[T_];
    __shared__ float ctx[H_], reg[H_];
    int tid = threadIdx.x;  // 64 threads

    if (tid < H_) {
        for (int t = 0; t < T_; ++t) {
            seq[t][tid] = pooled[t * H_ + tid] / (float)N_;
            float acc = bgp[tid];
            for (int k = 0; k < G_; ++k) acc += Wgp[tid * G_ + k] * gf_all[t * G_ + k];
            seq[t][H_ + tid] = fmaxf(acc, 0.0f);
        }
        hstate[tid] = 0.0f;
    }
    __syncthreads();

    for (int t = 0; t < T_; ++t) {
        if (tid < H_) {
            float gi_r = b_ih[tid], gi_z = b_ih[H_ + tid], gi_n = b_ih[2 * H_ + tid];
            for (int k = 0; k < 2 * H_; ++k) {
                float xv = seq[t][k];
                gi_r += W_ih[tid * 2 * H_ + k] * xv;
                gi_z += W_ih[(H_ + tid) * 2 * H_ + k] * xv;
                gi_n += W_ih[(2 * H_ + tid) * 2 * H_ + k] * xv;
            }
            float gh_r = b_hh[tid], gh_z = b_hh[H_ + tid], gh_n = b_hh[2 * H_ + tid];
            for (int k = 0; k < H_; ++k) {
                float hv = hstate[k];
                gh_r += W_hh[tid * H_ + k] * hv;
                gh_z += W_hh[(H_ + tid) * H_ + k] * hv;
                gh_n += W_hh[(2 * H_ + tid) * H_ + k] * hv;
            }
            float r = 1.0f / (1.0f + expf(-(gi_r + gh_r)));
            float z = 1.0f / (1.0f + expf(-(gi_z + gh_z)));
            float nn = tanhf(gi_n + r * gh_n);
            tmp[tid] = (1.0f - z) * nn + z * hstate[tid];
        }
        __syncthreads();
        if (tid < H_) {
            hstate[tid] = tmp[tid];
            gout[t][tid] = tmp[tid];
        }
        __syncthreads();
    }

    if (tid < T_) {
        float s = ba[0], m = btm[0];
        for (int k = 0; k < H_; ++k) {
            s += Wa[k] * gout[tid][k];
            m += Wtm[k] * gout[tid][k];
        }
        scores[tid] = s;
        tmask[tid] = 1.0f / (1.0f + expf(-m));
    }
    __syncthreads();
    if (tid == 0) {
        float mx = scores[0];
        for (int t = 1; t < T_; ++t) mx = fmaxf(mx, scores[t]);
        float sum = 0.0f;
        for (int t = 0; t < T_; ++t) { wts[t] = expf(scores[t] - mx); sum += wts[t]; }
        for (int t = 0; t < T_; ++t) {
            wts[t] /= sum;
            out[1 + t] = wts[t];
            out[17 + (size_t)T_ * N_ * H_ + t] = tmask[t];
        }
    }
    __syncthreads();
    if (tid < H_) {
        float c = 0.0f;
        for (int t = 0; t < T_; ++t) c += gout[t][tid] * wts[t] * tmask[t];
        ctx[tid] = c;
    }
    __syncthreads();
    if (tid < H_) {
        float acc = br1[tid];
        for (int k = 0; k < H_; ++k) acc += Wr1[tid * H_ + k] * ctx[k];
        reg[tid] = fmaxf(acc, 0.0f);
    }
    __syncthreads();
    if (tid == 0) {
        float p = br2[0];
        for (int k = 0; k < H_; ++k) p += Wr2[k] * reg[k];
        out[0] = p;
        float m[F_];
        for (int f = 0; f < F_; ++f) {
            float s = 0.0f;
            for (int h = 0; h < H_; ++h) s += fabsf(Ws1[h * F_ + f]);
            m[f] = s / (float)H_;
        }
        for (int i = 0; i < 8; ++i) {
            int best = i;
            for (int j = i + 1; j < F_; ++j)
                if (m[j] > m[best]) best = j;
            float tv = m[i]; m[i] = m[best]; m[best] = tv;
            out[9 + i] = m[i];
        }
    }
}

extern "C" void kernel_launch(void* const* d_in, const int* in_sizes, int n_in,
                              void* d_out, int out_size, void* d_ws, size_t ws_size,
                              hipStream_t stream) {
    const float* node_features  = (const float*)d_in[0];
    const int*   edge_index     = (const int*)d_in[1];
    const float* graph_features = (const float*)d_in[2];
    const float* Ws1 = (const float*)d_in[3];
    const float* bs1 = (const float*)d_in[4];
    const float* Wn1 = (const float*)d_in[5];
    const float* bn1 = (const float*)d_in[6];
    const float* Ws2 = (const float*)d_in[7];
    const float* bs2 = (const float*)d_in[8];
    const float* Wn2 = (const float*)d_in[9];
    const float* bn2 = (const float*)d_in[10];
    const float* Wgp = (const float*)d_in[11];
    const float* bgp = (const float*)d_in[12];
    const float* W_ih = (const float*)d_in[13];
    const float* b_ih = (const float*)d_in[14];
    const float* W_hh = (const float*)d_in[15];
    const float* b_hh = (const float*)d_in[16];
    const float* Wa  = (const float*)d_in[17];
    const float* ba  = (const float*)d_in[18];
    const float* Wsm = (const float*)d_in[19];
    const float* bsm = (const float*)d_in[20];
    const float* Wtm = (const float*)d_in[21];
    const float* btm = (const float*)d_in[22];
    const float* Wr1 = (const float*)d_in[23];
    const float* br1 = (const float*)d_in[24];
    const float* Wr2 = (const float*)d_in[25];
    const float* br2 = (const float*)d_in[26];

    // workspace layout (~49 MB)
    int* cnt   = (int*)d_ws;                         // N (count -> cursor)
    int* rowp  = cnt + N_;                           // N+1
    int* bsum  = rowp + (N_ + 1);                    // 128
    int* srcs  = bsum + 128;                         // E
    float* h1      = (float*)(srcs + E_);            // N*H
    float* neigh   = h1 + (size_t)N_ * H_;           // N*H (conv1 uses [N][FP] prefix)
    float* partial = neigh + (size_t)N_ * H_;        // T*H*CONV_GRID
    float* pooled  = partial + (size_t)T_ * H_ * CONV_GRID;  // T*H

    float* out = (float*)d_out;

    const int AGG_BLOCKS = (N_ + NPW * 4 - 1) / (NPW * 4);   // 4 waves/block

    for (int t = 0; t < T_; ++t) {
        const float* x   = node_features + (size_t)t * N_ * F_;
        const int*   src = edge_index + (size_t)t * 2 * E_;
        const int*   dst = src + E_;

        hipMemsetAsync(cnt, 0, N_ * sizeof(int), stream);
        k_count<<<(E_ + 255) / 256, 256, 0, stream>>>(dst, cnt);
        k_scan1<<<SCAN_NB, 256, 0, stream>>>(cnt, bsum);
        k_scan2<<<1, 64, 0, stream>>>(bsum, rowp);
        k_scan3<<<SCAN_NB, 256, 0, stream>>>(cnt, bsum, rowp);
        k_fill<<<(E_ + 255) / 256, 256, 0, stream>>>(src, dst, cnt, srcs);

        k_aggW<F_, F_, FP><<<AGG_BLOCKS, 256, 0, stream>>>(x, rowp, srcs, neigh);
        k_conv1T<<<CONV_GRID, 192, 0, stream>>>(x, neigh, Ws1, bs1, Wn1, bn1, h1);
        k_aggW<H_, H_, H_><<<AGG_BLOCKS, 256, 0, stream>>>(h1, rowp, srcs, neigh);
        float* sm_out = out + 17 + (size_t)t * N_ * H_;
        k_conv2T<<<CONV_GRID, 192, 0, stream>>>(h1, neigh, Ws2, bs2, Wn2, bn2,
                                                Wsm, bsm, sm_out,
                                                partial + (size_t)t * H_ * CONV_GRID);
    }

    k_reduce<<<T_ * H_, 256, 0, stream>>>(partial, pooled);
    k_final<<<1, 64, 0, stream>>>(graph_features, pooled, Wgp, bgp,
                                  W_ih, b_ih, W_hh, b_hh, Wa, ba, Wtm, btm,
                                  Wr1, br1, Wr2, br2, Ws1, out);
}